// Round 1
// baseline (500.188 us; speedup 1.0000x reference)
//
#include <hip/hip_runtime.h>
#include <hip/hip_bf16.h>

typedef unsigned short u16;
typedef __attribute__((ext_vector_type(8))) short short8;
typedef __attribute__((ext_vector_type(4))) float f32x4;

#define B_ 8
#define V_ 64
#define T_ 256
#define T1_ 257
#define D_ 256
#define H_ 8
#define DH_ 32

__device__ __forceinline__ u16 f2bf(float f){
  union { float f; unsigned int u; } v; v.f = f;
  unsigned int u = v.u;
  return (u16)((u + 0x7fffu + ((u >> 16) & 1u)) >> 16);
}

// ---------------- kernel 0: weights -> bf16 ----------------
__global__ void k0_conv(const float* __restrict__ wqkv, const float* __restrict__ wproj,
                        u16* __restrict__ wv, u16* __restrict__ wp){
  int i = blockIdx.x * 256 + threadIdx.x;   // 512 blocks -> 131072
  if (i < 65536) wv[i] = f2bf(wqkv[131072 + i]);     // rows 512..767 = Wv
  else           wp[i - 65536] = f2bf(wproj[i - 65536]);
}

__global__ void k_zero(float* __restrict__ p, int n){
  int i = blockIdx.x * blockDim.x + threadIdx.x;
  if (i < n) p[i] = 0.f;
}

// ---------------- kernel 1: LN stats + masked xn-sum ----------------
// grid (B*V, 9), block 256. Writes musig[(bv*257+t)*2 +{0,1}] = mu,rstd; atomically adds masked xn sum.
__global__ void k1_ln(const float* __restrict__ x, const int* __restrict__ mask,
                      const float* __restrict__ lnw, const float* __restrict__ lnb,
                      float* __restrict__ musig, float* __restrict__ xsum){
  int bv = blockIdx.x;
  int t0 = blockIdx.y * 29;
  int tend = t0 + 29; if (tend > T1_) tend = T1_;
  int tid = threadIdx.x;
  int lane = tid & 63, wid = tid >> 6;
  __shared__ float red[8];
  float w = lnw[tid], bp = lnb[tid];
  float xs_local = 0.f;
  for (int t = t0; t < tend; ++t){
    float v = x[((long)bv * T1_ + t) * D_ + tid];
    float s = v, s2 = v * v;
    #pragma unroll
    for (int off = 32; off >= 1; off >>= 1){
      s  += __shfl_down(s,  off, 64);
      s2 += __shfl_down(s2, off, 64);
    }
    if (lane == 0){ red[wid] = s; red[4 + wid] = s2; }
    __syncthreads();
    float S  = red[0] + red[1] + red[2] + red[3];
    float S2 = red[4] + red[5] + red[6] + red[7];
    __syncthreads();
    float mu   = S * (1.f / 256.f);
    float var  = S2 * (1.f / 256.f) - mu * mu;
    float rstd = rsqrtf(var + 1e-5f);
    float xn = (v - mu) * rstd * w + bp;
    int m = (t == 0) ? 1 : mask[bv * T_ + (t - 1)];
    if (m) xs_local += xn;
    if (tid == 0){
      musig[((long)bv * T1_ + t) * 2]     = mu;
      musig[((long)bv * T1_ + t) * 2 + 1] = rstd;
    }
  }
  atomicAdd(&xsum[bv * D_ + tid], xs_local);
}

// ---------------- kernel 2a: q,k projections (tiny) ----------------
// grid 512 (one per (b,v)), block 256.
__global__ void k2a_qk(const float* __restrict__ x, const int* __restrict__ mask,
                       const float* __restrict__ lnw, const float* __restrict__ lnb,
                       const float* __restrict__ wqkv,
                       const float* __restrict__ musig, const float* __restrict__ xsum,
                       float* __restrict__ qout, float* __restrict__ kout){
  int bv = blockIdx.x, tid = threadIdx.x;
  int lane = tid & 63, wid = tid >> 6;
  __shared__ __align__(16) float xn0[D_];
  __shared__ __align__(16) float xs[D_];
  __shared__ float redc[4];
  int s = mask[bv * T_ + tid];
  #pragma unroll
  for (int off = 32; off >= 1; off >>= 1) s += __shfl_down(s, off, 64);
  if (lane == 0) redc[wid] = (float)s;
  __syncthreads();
  float cnt = 1.f + redc[0] + redc[1] + redc[2] + redc[3];  // >= 1 always
  float mu = musig[((long)bv * T1_) * 2], rstd = musig[((long)bv * T1_) * 2 + 1];
  xn0[tid] = (x[((long)bv * T1_) * D_ + tid] - mu) * rstd * lnw[tid] + lnb[tid];
  xs[tid]  = xsum[bv * D_ + tid] * (1.f / cnt);
  __syncthreads();
  float4 xq = *(const float4*)&xn0[lane * 4];
  float4 xk = *(const float4*)&xs[lane * 4];
  for (int i = 0; i < 64; ++i){
    int e = wid * 64 + i;
    float4 wq4 = *(const float4*)&wqkv[(long)e * D_ + lane * 4];
    float4 wk4 = *(const float4*)&wqkv[(long)(256 + e) * D_ + lane * 4];
    float sq = xq.x*wq4.x + xq.y*wq4.y + xq.z*wq4.z + xq.w*wq4.w;
    float sk = xk.x*wk4.x + xk.y*wk4.y + xk.z*wk4.z + xk.w*wk4.w;
    #pragma unroll
    for (int off = 32; off >= 1; off >>= 1){
      sq += __shfl_down(sq, off, 64);
      sk += __shfl_down(sk, off, 64);
    }
    if (lane == 0){ qout[bv * D_ + e] = sq; kout[bv * D_ + e] = sk; }
  }
}

// ---------------- kernel 2b: 64x64 attention per (b,h) ----------------
// grid 64, block 64. Writes attn bf16 [b][h][q][k].
__global__ void k2b_attn(const float* __restrict__ q, const float* __restrict__ k,
                         u16* __restrict__ attn){
  int bh = blockIdx.x; int b = bh >> 3, h = bh & 7;
  int tid = threadIdx.x;  // q row
  __shared__ float qs[64][DH_], ks[64][DH_];
  for (int d = 0; d < DH_; ++d){
    qs[tid][d] = q[((long)(b * V_ + tid)) * D_ + h * DH_ + d];
    ks[tid][d] = k[((long)(b * V_ + tid)) * D_ + h * DH_ + d];
  }
  __syncthreads();
  const float scale = 0.17677669529663687f;  // 1/sqrt(32)
  float sc[64];
  float mx = -1e30f;
  #pragma unroll
  for (int j = 0; j < 64; ++j){
    float a = 0.f;
    #pragma unroll
    for (int d = 0; d < DH_; ++d) a += qs[tid][d] * ks[j][d];
    a *= scale; sc[j] = a; mx = fmaxf(mx, a);
  }
  float sum = 0.f;
  #pragma unroll
  for (int j = 0; j < 64; ++j){ float e = __expf(sc[j] - mx); sc[j] = e; sum += e; }
  float inv = 1.f / sum;
  #pragma unroll
  for (int j = 0; j < 64; ++j) attn[((long)bh * 64 + tid) * 64 + j] = f2bf(sc[j] * inv);
}

// ---------------- kernel 3: fused LN -> V-proj -> attn-mix -> out-proj -> residual ----------------
// grid B*T1 (2056), block 256 (4 waves). Per block: one (b,t) slice of 64 vars x 256 dims.
__global__ __launch_bounds__(256, 2) void k3_main(
    const float* __restrict__ x, const float* __restrict__ lnw, const float* __restrict__ lnb,
    const float* __restrict__ bproj, const float* __restrict__ musig,
    const u16* __restrict__ wv, const u16* __restrict__ wp,
    const u16* __restrict__ attn, float* __restrict__ out){
  constexpr int XS = 264;   // row stride (bf16 elems) for Xs/Ms: 2-way-aliasing-free b128 reads
  constexpr int VS = 72;    // row stride for transposed vf
  __shared__ __align__(16) u16 Xs[64 * XS];    // xn slice; reused as mix (Ms)
  __shared__ __align__(16) u16 VT[D_ * VS];    // vf transposed: [col][var]
  __shared__ float lnw_s[D_], lnb_s[D_], bp_s[D_];
  __shared__ float ms_s[V_ * 2];

  int bt = blockIdx.x; int b = bt / T1_, t = bt % T1_;
  int tid = threadIdx.x;
  int w = tid >> 6, lane = tid & 63, lm = lane & 15, lq = lane >> 4;

  lnw_s[tid] = lnw[tid]; lnb_s[tid] = lnb[tid]; bp_s[tid] = bproj[tid];
  if (tid < 128) ms_s[tid] = musig[(((long)b * V_ + (tid >> 1)) * T1_ + t) * 2 + (tid & 1)];
  __syncthreads();

  // ---- stage x slice with LN applied, as bf16, into Xs ----
  #pragma unroll
  for (int i = 0; i < 8; ++i){
    int seg = i * 256 + tid;          // 2048 segments of 8 elems
    int vr = seg >> 5;
    int c8 = (seg & 31) * 8;
    const float* gp = x + (((long)b * V_ + vr) * T1_ + t) * D_ + c8;
    float4 a0 = *(const float4*)gp;
    float4 a1 = *(const float4*)(gp + 4);
    float mu = ms_s[vr * 2], rs = ms_s[vr * 2 + 1];
    float av[8] = {a0.x, a0.y, a0.z, a0.w, a1.x, a1.y, a1.z, a1.w};
    union { u16 us[8]; uint4 q; } pk;
    #pragma unroll
    for (int j = 0; j < 8; ++j)
      pk.us[j] = f2bf((av[j] - mu) * rs * lnw_s[c8 + j] + lnb_s[c8 + j]);
    *(uint4*)&Xs[vr * XS + c8] = pk.q;
  }
  __syncthreads();

  // ---- GEMM1: vf = Xs(64x256) @ Wv^T ; wave w owns cols [64w,64w+64) ----
  f32x4 acc1[4][4];
  #pragma unroll
  for (int mt = 0; mt < 4; ++mt)
    #pragma unroll
    for (int nt = 0; nt < 4; ++nt) acc1[mt][nt] = (f32x4){0.f, 0.f, 0.f, 0.f};
  for (int kk = 0; kk < 8; ++kk){
    short8 af[4], bfr[4];
    #pragma unroll
    for (int mt = 0; mt < 4; ++mt)
      af[mt] = *(const short8*)&Xs[(mt * 16 + lm) * XS + kk * 32 + lq * 8];
    #pragma unroll
    for (int nt = 0; nt < 4; ++nt)
      bfr[nt] = *(const short8*)&wv[(long)(w * 64 + nt * 16 + lm) * D_ + kk * 32 + lq * 8];
    #pragma unroll
    for (int mt = 0; mt < 4; ++mt)
      #pragma unroll
      for (int nt = 0; nt < 4; ++nt)
        acc1[mt][nt] = __builtin_amdgcn_mfma_f32_16x16x32_bf16(af[mt], bfr[nt], acc1[mt][nt], 0, 0, 0);
  }
  // write vf transposed (bf16): VT[col][var]
  #pragma unroll
  for (int mt = 0; mt < 4; ++mt)
    #pragma unroll
    for (int nt = 0; nt < 4; ++nt){
      int col = w * 64 + nt * 16 + lm;
      int row = mt * 16 + lq * 4;
      union { u16 us[4]; uint2 q; } pv;
      #pragma unroll
      for (int r = 0; r < 4; ++r) pv.us[r] = f2bf(acc1[mt][nt][r]);
      *(uint2*)&VT[col * VS + row] = pv.q;
    }
  __syncthreads();   // Xs reads done everywhere; VT complete

  // ---- mix: per head h=2w+hh: mix[q,c] = attn_h(64x64) @ vf[:,c] ----
  f32x4 acc2[2][4][2];
  #pragma unroll
  for (int hh = 0; hh < 2; ++hh)
    #pragma unroll
    for (int mt = 0; mt < 4; ++mt)
      #pragma unroll
      for (int nt = 0; nt < 2; ++nt) acc2[hh][mt][nt] = (f32x4){0.f, 0.f, 0.f, 0.f};
  #pragma unroll
  for (int hh = 0; hh < 2; ++hh){
    int h = w * 2 + hh;
    #pragma unroll
    for (int kk = 0; kk < 2; ++kk){
      short8 af[4], bfr[2];
      #pragma unroll
      for (int mt = 0; mt < 4; ++mt)
        af[mt] = *(const short8*)&attn[((long)(b * H_ + h) * 64 + mt * 16 + lm) * 64 + kk * 32 + lq * 8];
      #pragma unroll
      for (int nt = 0; nt < 2; ++nt)
        bfr[nt] = *(const short8*)&VT[(h * 32 + nt * 16 + lm) * VS + kk * 32 + lq * 8];
      #pragma unroll
      for (int mt = 0; mt < 4; ++mt)
        #pragma unroll
        for (int nt = 0; nt < 2; ++nt)
          acc2[hh][mt][nt] = __builtin_amdgcn_mfma_f32_16x16x32_bf16(af[mt], bfr[nt], acc2[hh][mt][nt], 0, 0, 0);
    }
  }
  // write mix into Ms (= Xs buffer), row-major
  #pragma unroll
  for (int hh = 0; hh < 2; ++hh)
    #pragma unroll
    for (int mt = 0; mt < 4; ++mt)
      #pragma unroll
      for (int nt = 0; nt < 2; ++nt){
        int col = (w * 2 + hh) * 32 + nt * 16 + lm;
        #pragma unroll
        for (int r = 0; r < 4; ++r){
          int row = mt * 16 + lq * 4 + r;
          Xs[row * XS + col] = f2bf(acc2[hh][mt][nt][r]);
        }
      }
  __syncthreads();

  // ---- GEMM3: out = Ms(64x256) @ Wproj^T ----
  f32x4 acc3[4][4];
  #pragma unroll
  for (int mt = 0; mt < 4; ++mt)
    #pragma unroll
    for (int nt = 0; nt < 4; ++nt) acc3[mt][nt] = (f32x4){0.f, 0.f, 0.f, 0.f};
  for (int kk = 0; kk < 8; ++kk){
    short8 af[4], bfr[4];
    #pragma unroll
    for (int mt = 0; mt < 4; ++mt)
      af[mt] = *(const short8*)&Xs[(mt * 16 + lm) * XS + kk * 32 + lq * 8];
    #pragma unroll
    for (int nt = 0; nt < 4; ++nt)
      bfr[nt] = *(const short8*)&wp[(long)(w * 64 + nt * 16 + lm) * D_ + kk * 32 + lq * 8];
    #pragma unroll
    for (int mt = 0; mt < 4; ++mt)
      #pragma unroll
      for (int nt = 0; nt < 4; ++nt)
        acc3[mt][nt] = __builtin_amdgcn_mfma_f32_16x16x32_bf16(af[mt], bfr[nt], acc3[mt][nt], 0, 0, 0);
  }
  // ---- epilogue: + b_proj + x, store fp32 ----
  #pragma unroll
  for (int mt = 0; mt < 4; ++mt)
    #pragma unroll
    for (int nt = 0; nt < 4; ++nt){
      int e = w * 64 + nt * 16 + lm;
      #pragma unroll
      for (int r = 0; r < 4; ++r){
        int vr = mt * 16 + lq * 4 + r;
        long g = (((long)b * V_ + vr) * T1_ + t) * D_ + e;
        out[g] = acc3[mt][nt][r] + bp_s[e] + x[g];
      }
    }
}

// ---------------- launch ----------------
extern "C" void kernel_launch(void* const* d_in, const int* in_sizes, int n_in,
                              void* d_out, int out_size, void* d_ws, size_t ws_size,
                              hipStream_t stream){
  const float* x     = (const float*)d_in[0];
  const int*   mask  = (const int*)d_in[1];
  const float* lnw   = (const float*)d_in[2];
  const float* lnb   = (const float*)d_in[3];
  const float* wqkv  = (const float*)d_in[4];
  const float* wproj = (const float*)d_in[5];
  const float* bproj = (const float*)d_in[6];
  float* out = (float*)d_out;
  char* ws = (char*)d_ws;
  // workspace layout (bytes)
  float* musig = (float*)(ws);              // 263168 f = 1,052,672 B
  float* xsum  = (float*)(ws + 1052672);    // 131072 f
  float* qbuf  = (float*)(ws + 1576960);    // 131072 f
  float* kbuf  = (float*)(ws + 2101248);    // 131072 f
  u16*   attn  = (u16*)  (ws + 2625536);    // 262144 u16
  u16*   wv    = (u16*)  (ws + 3149824);    // 65536 u16
  u16*   wp    = (u16*)  (ws + 3280896);    // 65536 u16

  k0_conv<<<512, 256, 0, stream>>>(wqkv, wproj, wv, wp);
  k_zero<<<512, 256, 0, stream>>>(xsum, 131072);
  k1_ln<<<dim3(512, 9), 256, 0, stream>>>(x, mask, lnw, lnb, musig, xsum);
  k2a_qk<<<512, 256, 0, stream>>>(x, mask, lnw, lnb, wqkv, musig, xsum, qbuf, kbuf);
  k2b_attn<<<64, 64, 0, stream>>>(qbuf, kbuf, attn);
  k3_main<<<B_ * T1_, 256, 0, stream>>>(x, lnw, lnb, bproj, musig, wv, wp, attn, out);
}

// Round 2
// 405.922 us; speedup vs baseline: 1.2322x; 1.2322x over previous
//
#include <hip/hip_runtime.h>
#include <hip/hip_bf16.h>

typedef unsigned short u16;
typedef __attribute__((ext_vector_type(8))) short short8;
typedef __attribute__((ext_vector_type(4))) float f32x4;

#define B_ 8
#define V_ 64
#define T_ 256
#define T1_ 257
#define D_ 256
#define H_ 8
#define DH_ 32

__device__ __forceinline__ u16 f2bf(float f){
  union { float f; unsigned int u; } v; v.f = f;
  unsigned int u = v.u;
  return (u16)((u + 0x7fffu + ((u >> 16) & 1u)) >> 16);
}

// ---------------- kernel 0: weights -> bf16 ----------------
__global__ void k0_conv(const float* __restrict__ wqkv, const float* __restrict__ wproj,
                        u16* __restrict__ wv, u16* __restrict__ wp){
  int i = blockIdx.x * 256 + threadIdx.x;   // 512 blocks -> 131072
  if (i < 65536) wv[i] = f2bf(wqkv[131072 + i]);     // rows 512..767 = Wv
  else           wp[i - 65536] = f2bf(wproj[i - 65536]);
}

__global__ void k_zero(float* __restrict__ p, int n){
  int i = blockIdx.x * blockDim.x + threadIdx.x;
  if (i < n) p[i] = 0.f;
}

// ---------------- kernel 1: LN stats + masked xn-sum ----------------
// grid (B*V, 4), block 256 = 4 waves. One WAVE per t (float4/lane, butterfly
// shuffle reduce, no in-loop barriers). y-block covers 65 t's (4 waves stride 4).
__global__ void k1_ln(const float* __restrict__ x, const int* __restrict__ mask,
                      const float* __restrict__ lnw, const float* __restrict__ lnb,
                      float* __restrict__ musig, float* __restrict__ xsum){
  int bv = blockIdx.x;
  int tid = threadIdx.x;
  int lane = tid & 63, wid = tid >> 6;
  int t0 = blockIdx.y * 65;
  int tend = t0 + 65; if (tend > T1_) tend = T1_;
  __shared__ float xsred[4][D_];
  float4 w4 = *(const float4*)&lnw[lane * 4];
  float4 b4 = *(const float4*)&lnb[lane * 4];
  float xs0 = 0.f, xs1 = 0.f, xs2 = 0.f, xs3 = 0.f;
  for (int t = t0 + wid; t < tend; t += 4){
    float4 v = *(const float4*)&x[((long)bv * T1_ + t) * D_ + lane * 4];
    float s  = v.x + v.y + v.z + v.w;
    float s2 = v.x*v.x + v.y*v.y + v.z*v.z + v.w*v.w;
    #pragma unroll
    for (int off = 1; off < 64; off <<= 1){
      s  += __shfl_xor(s,  off, 64);
      s2 += __shfl_xor(s2, off, 64);
    }
    float mu   = s * (1.f / 256.f);
    float var  = s2 * (1.f / 256.f) - mu * mu;
    float rstd = rsqrtf(var + 1e-5f);
    if (lane == 0){
      musig[((long)bv * T1_ + t) * 2]     = mu;
      musig[((long)bv * T1_ + t) * 2 + 1] = rstd;
    }
    int m = (t == 0) ? 1 : mask[bv * T_ + (t - 1)];
    if (m){
      xs0 += (v.x - mu) * rstd * w4.x + b4.x;
      xs1 += (v.y - mu) * rstd * w4.y + b4.y;
      xs2 += (v.z - mu) * rstd * w4.z + b4.z;
      xs3 += (v.w - mu) * rstd * w4.w + b4.w;
    }
  }
  xsred[wid][lane * 4]     = xs0;
  xsred[wid][lane * 4 + 1] = xs1;
  xsred[wid][lane * 4 + 2] = xs2;
  xsred[wid][lane * 4 + 3] = xs3;
  __syncthreads();
  float r = xsred[0][tid] + xsred[1][tid] + xsred[2][tid] + xsred[3][tid];
  atomicAdd(&xsum[bv * D_ + tid], r);
}

// ---------------- kernel 2a: q,k projections (tiny) ----------------
// grid (512, 4), block 256 = 4 waves. Wave (y*4+wid) computes 16 outputs.
__global__ void k2a_qk(const float* __restrict__ x, const int* __restrict__ mask,
                       const float* __restrict__ lnw, const float* __restrict__ lnb,
                       const float* __restrict__ wqkv,
                       const float* __restrict__ musig, const float* __restrict__ xsum,
                       float* __restrict__ qout, float* __restrict__ kout){
  int bv = blockIdx.x, tid = threadIdx.x;
  int lane = tid & 63, wid = tid >> 6;
  __shared__ __align__(16) float xn0[D_];
  __shared__ __align__(16) float xs[D_];
  __shared__ float redc[4];
  int s = mask[bv * T_ + tid];
  #pragma unroll
  for (int off = 32; off >= 1; off >>= 1) s += __shfl_down(s, off, 64);
  if (lane == 0) redc[wid] = (float)s;
  __syncthreads();
  float cnt = 1.f + redc[0] + redc[1] + redc[2] + redc[3];
  float mu = musig[((long)bv * T1_) * 2], rstd = musig[((long)bv * T1_) * 2 + 1];
  xn0[tid] = (x[((long)bv * T1_) * D_ + tid] - mu) * rstd * lnw[tid] + lnb[tid];
  xs[tid]  = xsum[bv * D_ + tid] * (1.f / cnt);
  __syncthreads();
  float4 xq = *(const float4*)&xn0[lane * 4];
  float4 xk = *(const float4*)&xs[lane * 4];
  int e0 = (blockIdx.y * 4 + wid) * 16;
  for (int i = 0; i < 16; ++i){
    int e = e0 + i;
    float4 wq4 = *(const float4*)&wqkv[(long)e * D_ + lane * 4];
    float4 wk4 = *(const float4*)&wqkv[(long)(256 + e) * D_ + lane * 4];
    float sq = xq.x*wq4.x + xq.y*wq4.y + xq.z*wq4.z + xq.w*wq4.w;
    float sk = xk.x*wk4.x + xk.y*wk4.y + xk.z*wk4.z + xk.w*wk4.w;
    #pragma unroll
    for (int off = 32; off >= 1; off >>= 1){
      sq += __shfl_down(sq, off, 64);
      sk += __shfl_down(sk, off, 64);
    }
    if (lane == 0){ qout[bv * D_ + e] = sq; kout[bv * D_ + e] = sk; }
  }
}

// ---------------- kernel 2b: 64x64 attention per (b,h) ----------------
__global__ void k2b_attn(const float* __restrict__ q, const float* __restrict__ k,
                         u16* __restrict__ attn){
  int bh = blockIdx.x; int b = bh >> 3, h = bh & 7;
  int tid = threadIdx.x;  // q row
  __shared__ float qs[64][DH_], ks[64][DH_];
  for (int d = 0; d < DH_; ++d){
    qs[tid][d] = q[((long)(b * V_ + tid)) * D_ + h * DH_ + d];
    ks[tid][d] = k[((long)(b * V_ + tid)) * D_ + h * DH_ + d];
  }
  __syncthreads();
  const float scale = 0.17677669529663687f;  // 1/sqrt(32)
  float sc[64];
  float mx = -1e30f;
  #pragma unroll
  for (int j = 0; j < 64; ++j){
    float a = 0.f;
    #pragma unroll
    for (int d = 0; d < DH_; ++d) a += qs[tid][d] * ks[j][d];
    a *= scale; sc[j] = a; mx = fmaxf(mx, a);
  }
  float sum = 0.f;
  #pragma unroll
  for (int j = 0; j < 64; ++j){ float e = __expf(sc[j] - mx); sc[j] = e; sum += e; }
  float inv = 1.f / sum;
  #pragma unroll
  for (int j = 0; j < 64; ++j) attn[((long)bh * 64 + tid) * 64 + j] = f2bf(sc[j] * inv);
}

// ---------------- kernel 3: fused LN -> V-proj -> attn-mix -> out-proj -> residual ----------------
// grid B*T1 (2056), block 512 (8 waves). Wave w owns output cols [32w,32w+32)
// in GEMM1/GEMM3 and head h=w in the mix. 74 KB LDS -> 2 blocks/CU = 16 waves/CU.
__global__ __launch_bounds__(512, 4) void k3_main(
    const float* __restrict__ x, const float* __restrict__ lnw, const float* __restrict__ lnb,
    const float* __restrict__ bproj, const float* __restrict__ musig,
    const u16* __restrict__ wv, const u16* __restrict__ wp,
    const u16* __restrict__ attn, float* __restrict__ out){
  constexpr int XS = 264;   // row stride (bf16 elems) for Xs/Ms
  constexpr int VS = 72;    // row stride for transposed vf
  __shared__ __align__(16) u16 Xs[64 * XS];    // xn slice; reused as mix (Ms)
  __shared__ __align__(16) u16 VT[D_ * VS];    // vf transposed: [col][var]
  __shared__ float lnw_s[D_], lnb_s[D_], bp_s[D_];
  __shared__ float ms_s[V_ * 2];

  int bt = blockIdx.x; int b = bt / T1_, t = bt % T1_;
  int tid = threadIdx.x;
  int w = tid >> 6, lane = tid & 63, lm = lane & 15, lq = lane >> 4;
  int cw = w * 32;   // this wave's output-column base

  if (tid < 256){ lnw_s[tid] = lnw[tid]; lnb_s[tid] = lnb[tid]; bp_s[tid] = bproj[tid]; }
  else if (tid < 384){
    int i = tid - 256;
    ms_s[i] = musig[(((long)b * V_ + (i >> 1)) * T1_ + t) * 2 + (i & 1)];
  }
  __syncthreads();

  // ---- stage x slice with LN applied, as bf16, into Xs ----
  #pragma unroll
  for (int i = 0; i < 4; ++i){
    int seg = i * 512 + tid;          // 2048 segments of 8 elems
    int vr = seg >> 5;
    int c8 = (seg & 31) * 8;
    const float* gp = x + (((long)b * V_ + vr) * T1_ + t) * D_ + c8;
    float4 a0 = *(const float4*)gp;
    float4 a1 = *(const float4*)(gp + 4);
    float mu = ms_s[vr * 2], rs = ms_s[vr * 2 + 1];
    float av[8] = {a0.x, a0.y, a0.z, a0.w, a1.x, a1.y, a1.z, a1.w};
    union { u16 us[8]; uint4 q; } pk;
    #pragma unroll
    for (int j = 0; j < 8; ++j)
      pk.us[j] = f2bf((av[j] - mu) * rs * lnw_s[c8 + j] + lnb_s[c8 + j]);
    *(uint4*)&Xs[vr * XS + c8] = pk.q;
  }
  __syncthreads();

  // ---- GEMM1: vf = Xs(64x256) @ Wv^T ; wave w -> cols [32w,32w+32) ----
  f32x4 acc1[4][2];
  #pragma unroll
  for (int mt = 0; mt < 4; ++mt)
    #pragma unroll
    for (int nt = 0; nt < 2; ++nt) acc1[mt][nt] = (f32x4){0.f, 0.f, 0.f, 0.f};
  for (int kk = 0; kk < 8; ++kk){
    short8 af[4], bfr[2];
    #pragma unroll
    for (int mt = 0; mt < 4; ++mt)
      af[mt] = *(const short8*)&Xs[(mt * 16 + lm) * XS + kk * 32 + lq * 8];
    #pragma unroll
    for (int nt = 0; nt < 2; ++nt)
      bfr[nt] = *(const short8*)&wv[(long)(cw + nt * 16 + lm) * D_ + kk * 32 + lq * 8];
    #pragma unroll
    for (int mt = 0; mt < 4; ++mt)
      #pragma unroll
      for (int nt = 0; nt < 2; ++nt)
        acc1[mt][nt] = __builtin_amdgcn_mfma_f32_16x16x32_bf16(af[mt], bfr[nt], acc1[mt][nt], 0, 0, 0);
  }
  // write vf transposed (bf16): VT[col][var]
  #pragma unroll
  for (int mt = 0; mt < 4; ++mt)
    #pragma unroll
    for (int nt = 0; nt < 2; ++nt){
      int col = cw + nt * 16 + lm;
      int row = mt * 16 + lq * 4;
      union { u16 us[4]; uint2 q; } pv;
      #pragma unroll
      for (int r = 0; r < 4; ++r) pv.us[r] = f2bf(acc1[mt][nt][r]);
      *(uint2*)&VT[col * VS + row] = pv.q;
    }
  __syncthreads();   // Xs reads done everywhere; VT complete

  // ---- mix: head h=w: mix[q,c] = attn_h(64x64) @ vf[:,c] for c in head h ----
  int h = w;
  f32x4 acc2[4][2];
  #pragma unroll
  for (int mt = 0; mt < 4; ++mt)
    #pragma unroll
    for (int nt = 0; nt < 2; ++nt) acc2[mt][nt] = (f32x4){0.f, 0.f, 0.f, 0.f};
  #pragma unroll
  for (int kk = 0; kk < 2; ++kk){
    short8 af[4], bfr[2];
    #pragma unroll
    for (int mt = 0; mt < 4; ++mt)
      af[mt] = *(const short8*)&attn[((long)(b * H_ + h) * 64 + mt * 16 + lm) * 64 + kk * 32 + lq * 8];
    #pragma unroll
    for (int nt = 0; nt < 2; ++nt)
      bfr[nt] = *(const short8*)&VT[(h * 32 + nt * 16 + lm) * VS + kk * 32 + lq * 8];
    #pragma unroll
    for (int mt = 0; mt < 4; ++mt)
      #pragma unroll
      for (int nt = 0; nt < 2; ++nt)
        acc2[mt][nt] = __builtin_amdgcn_mfma_f32_16x16x32_bf16(af[mt], bfr[nt], acc2[mt][nt], 0, 0, 0);
  }
  // write mix into Ms (= Xs buffer), row-major; wave w writes cols [32w,32w+32)
  #pragma unroll
  for (int mt = 0; mt < 4; ++mt)
    #pragma unroll
    for (int nt = 0; nt < 2; ++nt){
      int col = h * 32 + nt * 16 + lm;
      #pragma unroll
      for (int r = 0; r < 4; ++r){
        int row = mt * 16 + lq * 4 + r;
        Xs[row * XS + col] = f2bf(acc2[mt][nt][r]);
      }
    }
  __syncthreads();

  // ---- GEMM3: out = Ms(64x256) @ Wproj^T ----
  f32x4 acc3[4][2];
  #pragma unroll
  for (int mt = 0; mt < 4; ++mt)
    #pragma unroll
    for (int nt = 0; nt < 2; ++nt) acc3[mt][nt] = (f32x4){0.f, 0.f, 0.f, 0.f};
  for (int kk = 0; kk < 8; ++kk){
    short8 af[4], bfr[2];
    #pragma unroll
    for (int mt = 0; mt < 4; ++mt)
      af[mt] = *(const short8*)&Xs[(mt * 16 + lm) * XS + kk * 32 + lq * 8];
    #pragma unroll
    for (int nt = 0; nt < 2; ++nt)
      bfr[nt] = *(const short8*)&wp[(long)(cw + nt * 16 + lm) * D_ + kk * 32 + lq * 8];
    #pragma unroll
    for (int mt = 0; mt < 4; ++mt)
      #pragma unroll
      for (int nt = 0; nt < 2; ++nt)
        acc3[mt][nt] = __builtin_amdgcn_mfma_f32_16x16x32_bf16(af[mt], bfr[nt], acc3[mt][nt], 0, 0, 0);
  }
  // ---- epilogue: + b_proj + x, store fp32 ----
  #pragma unroll
  for (int mt = 0; mt < 4; ++mt)
    #pragma unroll
    for (int nt = 0; nt < 2; ++nt){
      int e = cw + nt * 16 + lm;
      #pragma unroll
      for (int r = 0; r < 4; ++r){
        int vr = mt * 16 + lq * 4 + r;
        long g = (((long)b * V_ + vr) * T1_ + t) * D_ + e;
        out[g] = acc3[mt][nt][r] + bp_s[e] + x[g];
      }
    }
}

// ---------------- launch ----------------
extern "C" void kernel_launch(void* const* d_in, const int* in_sizes, int n_in,
                              void* d_out, int out_size, void* d_ws, size_t ws_size,
                              hipStream_t stream){
  const float* x     = (const float*)d_in[0];
  const int*   mask  = (const int*)d_in[1];
  const float* lnw   = (const float*)d_in[2];
  const float* lnb   = (const float*)d_in[3];
  const float* wqkv  = (const float*)d_in[4];
  const float* wproj = (const float*)d_in[5];
  const float* bproj = (const float*)d_in[6];
  float* out = (float*)d_out;
  char* ws = (char*)d_ws;
  float* musig = (float*)(ws);              // 263168 f
  float* xsum  = (float*)(ws + 1052672);    // 131072 f
  float* qbuf  = (float*)(ws + 1576960);    // 131072 f
  float* kbuf  = (float*)(ws + 2101248);    // 131072 f
  u16*   attn  = (u16*)  (ws + 2625536);    // 262144 u16
  u16*   wv    = (u16*)  (ws + 3149824);    // 65536 u16
  u16*   wp    = (u16*)  (ws + 3280896);    // 65536 u16

  k0_conv<<<512, 256, 0, stream>>>(wqkv, wproj, wv, wp);
  k_zero<<<512, 256, 0, stream>>>(xsum, 131072);
  k1_ln<<<dim3(512, 4), 256, 0, stream>>>(x, mask, lnw, lnb, musig, xsum);
  k2a_qk<<<dim3(512, 4), 256, 0, stream>>>(x, mask, lnw, lnb, wqkv, musig, xsum, qbuf, kbuf);
  k2b_attn<<<64, 64, 0, stream>>>(qbuf, kbuf, attn);
  k3_main<<<B_ * T1_, 512, 0, stream>>>(x, lnw, lnb, bproj, musig, wv, wp, attn, out);
}